// Round 3
// baseline (6165.709 us; speedup 1.0000x reference)
//
#include <hip/hip_runtime.h>

#define NHID   128
#define NSTEPS 512
#define NSAMP  4096
#define SPB    16
#define BS     1024
#define NBLK   (NSAMP / SPB)          // 256 blocks, 1 per CU
#define HPAD   132                    // h row pad: 132%32=4 -> all accesses 2-way max
#define SAMP_ELEMS (NSAMP * NSTEPS)
#define WT_ELEMS   (3 * NHID * NHID)  // transposed weights, 196 KB

__global__ __launch_bounds__(256)
void transpose_w_kernel(const float* __restrict__ rk, float* __restrict__ wt) {
    const int i = blockIdx.x * 256 + threadIdx.x;
    if (i < WT_ELEMS) {
        const int c = i / (3 * NHID);      // channel
        const int r = i - c * 3 * NHID;
        const int g = r >> 7;              // gate
        const int k = r & (NHID - 1);      // k
        wt[i] = rk[k * 384 + g * NHID + c];
    }
}

template<int TR>
__global__ __launch_bounds__(BS, 4)
void vmc_gru_kernel(const float* __restrict__ gk,   // (2, 384)
                    const float* __restrict__ rk,   // (128, 384)
                    const float* __restrict__ gb,   // (2, 384)
                    const float* __restrict__ dw,   // (128, 2)
                    const float* __restrict__ db,   // (2,)
                    const float* __restrict__ u,    // (4096, 512)
                    const float* __restrict__ wt,   // (128, 3, 128) transposed
                    float* __restrict__ out)        // samples then logp
{
    __shared__ float hsm[2][SPB][HPAD];   // h double-buffered, [s][k]
    __shared__ float part[16][8][4];      // per-wave 8-channel logit partials
    __shared__ int   prevs[SPB];

    const int tid = threadIdx.x;
    const int cg  = tid >> 3;             // channel 0..127
    const int p   = tid & 7;              // sample-pair slot
    const int s0  = p * 2;
    const int wv  = tid >> 6;             // wave 0..15

    for (int i = tid; i < SPB * HPAD; i += BS) (&hsm[0][0][0])[i] = 0.0f;
    if (tid < SPB) prevs[tid] = 0;
    __syncthreads();

    // per-thread constants for channel cg
    const float brz = gb[384 + cg];
    const float brr = gb[384 + 128 + cg];
    const float brh = gb[384 + 256 + cg];
    const float xzI = gb[cg],       xz0c = xzI + gk[cg],       xz1c = xzI + gk[384 + cg];
    const float xrI = gb[128 + cg], xr0c = xrI + gk[128 + cg], xr1c = xrI + gk[384 + 128 + cg];
    const float xhI = gb[256 + cg], xh0c = xhI + gk[256 + cg], xh1c = xhI + gk[384 + 256 + cg];
    const float dwc0 = dw[cg * 2], dwc1 = dw[cg * 2 + 1];
    const float db0 = db[0], db1 = db[1];

    const int fsamp = blockIdx.x * SPB + tid;   // valid for tid < 16
    float logp = 0.0f;
    int cur = 0;

    const float* wtp = wt + cg * 384;     // [c][3][128]
    const float* rkp = rk + cg;

    for (int t = 0; t < NSTEPS; ++t) {
        // ---- GEMM: per (cg, 2 samples); chain bit-identical: bias init, k ascending
        float az0 = brz, az1 = brz;
        float ar0 = brr, ar1 = brr;
        float ah0 = brh, ah1 = brh;
        const float* h0p = &hsm[cur][s0][0];
        const float* h1p = &hsm[cur][s0 + 1][0];

        if (TR) {
            #pragma unroll 8
            for (int k4 = 0; k4 < NHID; k4 += 4) {
                const float4 wz = *(const float4*)(wtp + k4);
                const float4 wr = *(const float4*)(wtp + 128 + k4);
                const float4 wh = *(const float4*)(wtp + 256 + k4);
                const float4 ha = *(const float4*)(h0p + k4);
                const float4 hb = *(const float4*)(h1p + k4);
                az0 = fmaf(wz.x, ha.x, az0); az1 = fmaf(wz.x, hb.x, az1);
                ar0 = fmaf(wr.x, ha.x, ar0); ar1 = fmaf(wr.x, hb.x, ar1);
                ah0 = fmaf(wh.x, ha.x, ah0); ah1 = fmaf(wh.x, hb.x, ah1);
                az0 = fmaf(wz.y, ha.y, az0); az1 = fmaf(wz.y, hb.y, az1);
                ar0 = fmaf(wr.y, ha.y, ar0); ar1 = fmaf(wr.y, hb.y, ar1);
                ah0 = fmaf(wh.y, ha.y, ah0); ah1 = fmaf(wh.y, hb.y, ah1);
                az0 = fmaf(wz.z, ha.z, az0); az1 = fmaf(wz.z, hb.z, az1);
                ar0 = fmaf(wr.z, ha.z, ar0); ar1 = fmaf(wr.z, hb.z, ar1);
                ah0 = fmaf(wh.z, ha.z, ah0); ah1 = fmaf(wh.z, hb.z, ah1);
                az0 = fmaf(wz.w, ha.w, az0); az1 = fmaf(wz.w, hb.w, az1);
                ar0 = fmaf(wr.w, ha.w, ar0); ar1 = fmaf(wr.w, hb.w, ar1);
                ah0 = fmaf(wh.w, ha.w, ah0); ah1 = fmaf(wh.w, hb.w, ah1);
            }
        } else {
            const float* wp = rkp;
            #pragma unroll 4
            for (int k = 0; k < NHID; ++k) {
                const float wz = wp[0];
                const float wr = wp[NHID];
                const float wh = wp[2 * NHID];
                const float ha = h0p[k];
                const float hb = h1p[k];
                az0 = fmaf(wz, ha, az0); az1 = fmaf(wz, hb, az1);
                ar0 = fmaf(wr, ha, ar0); ar1 = fmaf(wr, hb, ar1);
                ah0 = fmaf(wh, ha, ah0); ah1 = fmaf(wh, hb, ah1);
                wp += 3 * NHID;
            }
        }

        // ---- gates + state update (writes go to the OTHER h buffer: no barrier needed)
        const int pv0 = prevs[s0], pv1 = prevs[s0 + 1];
        const float ho0 = hsm[cur][s0][cg];
        const float ho1 = hsm[cur][s0 + 1][cg];

        float xzA = pv0 ? xz1c : xz0c, xzB = pv1 ? xz1c : xz0c;
        float xrA = pv0 ? xr1c : xr0c, xrB = pv1 ? xr1c : xr0c;
        float xhA = pv0 ? xh1c : xh0c, xhB = pv1 ? xh1c : xh0c;
        if (t == 0) { xzA = xzI; xzB = xzI; xrA = xrI; xrB = xrI; xhA = xhI; xhB = xhI; }

        const float zA  = 1.0f / (1.0f + expf(-(xzA + az0)));
        const float rA  = 1.0f / (1.0f + expf(-(xrA + ar0)));
        const float hcA = tanhf(xhA + rA * ah0);
        const float hn0 = zA * ho0 + (1.0f - zA) * hcA;

        const float zB  = 1.0f / (1.0f + expf(-(xzB + az1)));
        const float rB  = 1.0f / (1.0f + expf(-(xrB + ar1)));
        const float hcB = tanhf(xhB + rB * ah1);
        const float hn1 = zB * ho1 + (1.0f - zB) * hcB;

        hsm[cur ^ 1][s0][cg]     = hn0;
        hsm[cur ^ 1][s0 + 1][cg] = hn1;

        float p00 = hn0 * dwc0, p01 = hn1 * dwc0;
        float p10 = hn0 * dwc1, p11 = hn1 * dwc1;

        // butterfly over the wave's 8 channels (cg bits at lane bits 3,4,5)
        #pragma unroll
        for (int off = 8; off < 64; off <<= 1) {
            p00 += __shfl_xor(p00, off);
            p01 += __shfl_xor(p01, off);
            p10 += __shfl_xor(p10, off);
            p11 += __shfl_xor(p11, off);
        }
        if ((tid & 63) < 8) {
            *(float4*)&part[wv][p][0] = make_float4(p00, p01, p10, p11);
        }
        __syncthreads();   // B1: partials + h_new visible

        // ---- softmax/sample/logp: one thread per sample
        // fold matches R2 bitwise: l = db + sum_j (T8[2j] + T8[2j+1])
        if (tid < SPB) {
            const int sh = tid >> 1, lo = tid & 1;
            float l0 = db0, l1 = db1;
            #pragma unroll
            for (int j = 0; j < 8; ++j) {
                const float4 qa = *(const float4*)&part[2 * j][sh][0];
                const float4 qb = *(const float4*)&part[2 * j + 1][sh][0];
                const float a0 = lo ? qa.y : qa.x;
                const float b0 = lo ? qb.y : qb.x;
                const float a1 = lo ? qa.w : qa.z;
                const float b1 = lo ? qb.w : qb.z;
                l0 += (a0 + b0);
                l1 += (a1 + b1);
            }
            const float mx = fmaxf(l0, l1);
            const float e0 = expf(l0 - mx);
            const float e1 = expf(l1 - mx);
            const float inv = 1.0f / (e0 + e1);
            const float p1 = e1 * inv;
            const float ut = u[(size_t)fsamp * NSTEPS + t];
            const int st = (ut < p1) ? 1 : 0;
            const float psel = st ? p1 : (e0 * inv);
            logp += logf(psel + 1e-10f);
            out[(size_t)fsamp * NSTEPS + t] = (float)st;
            prevs[tid] = st;
        }
        __syncthreads();   // B2: prevs/sample published before next step
        cur ^= 1;
    }

    if (tid < SPB) out[SAMP_ELEMS + fsamp] = logp;
}

extern "C" void kernel_launch(void* const* d_in, const int* in_sizes, int n_in,
                              void* d_out, int out_size, void* d_ws, size_t ws_size,
                              hipStream_t stream) {
    const float* gk = (const float*)d_in[0];
    const float* rk = (const float*)d_in[1];
    const float* gb = (const float*)d_in[2];
    const float* dw = (const float*)d_in[3];
    const float* db = (const float*)d_in[4];
    const float* u  = (const float*)d_in[5];
    float* out = (float*)d_out;

    if (ws_size >= (size_t)WT_ELEMS * sizeof(float)) {
        float* wt = (float*)d_ws;
        transpose_w_kernel<<<(WT_ELEMS + 255) / 256, 256, 0, stream>>>(rk, wt);
        vmc_gru_kernel<1><<<NBLK, BS, 0, stream>>>(gk, rk, gb, dw, db, u, wt, out);
    } else {
        vmc_gru_kernel<0><<<NBLK, BS, 0, stream>>>(gk, rk, gb, dw, db, u, rk, out);
    }
}